// Round 19
// baseline (460.609 us; speedup 1.0000x reference)
//
#include <hip/hip_runtime.h>
#include <stdint.h>

#define LSEQ 32768
#define NCH 512      // scan chunks
#define TCH 64       // timesteps per chunk  (NCH*TCH == LSEQ)

typedef _Float16 half8 __attribute__((ext_vector_type(8)));
typedef _Float16 half4v __attribute__((ext_vector_type(4)));
typedef _Float16 half2v __attribute__((ext_vector_type(2)));
typedef float f32x4 __attribute__((ext_vector_type(4)));
typedef float f32x2 __attribute__((ext_vector_type(2)));

__device__ __forceinline__ float sigmoidf_(float x) { return 1.f / (1.f + __expf(-x)); }
__device__ __forceinline__ float gelu_(float x) {
    float z = 0.7978845608028654f * (x + 0.044715f * x * x * x);
    float e = __expf(2.f * z);
    float t = 1.f - 2.f / (e + 1.f);   // tanh(z)
    return 0.5f * x * (1.f + t);
}

// async global->LDS, 16B per lane. LDS dest is wave-uniform base; HW writes
// base + lane*16 (matches the fragment-major chunk layout below).
__device__ __forceinline__ void gll16(const _Float16* gp, _Float16* lp) {
    __builtin_amdgcn_global_load_lds((__attribute__((address_space(1))) void*)gp,
                                     (__attribute__((address_space(3))) void*)lp, 16, 0, 0);
}

// --------------------------- setup kernels ---------------------------------
__global__ __launch_bounds__(512) void s5_k0a(const float* __restrict__ lre, const float* __restrict__ lim,
                                              const float* __restrict__ lstep,
                                              float* aR, float* aI, float* cbR, float* cbI,
                                              float* aTR, float* aTI, float* alp, float* ralp) {
    int i = threadIdx.x;  // 4 layers * 128 channels
    float st = expf(lstep[i]);
    float lr = lre[i] * st, li = lim[i] * st;
    float ea = expf(lr);
    float ar = ea * cosf(li), ai = ea * sinf(li);
    float den = lre[i] * lre[i] + lim[i] * lim[i];
    float nr = ar - 1.f, ni = ai;
    float cr = (nr * lre[i] + ni * lim[i]) / den;   // (a-1)/Lambda
    float ci = (ni * lre[i] - nr * lim[i]) / den;
    float cm = sqrtf(cr * cr + ci * ci);
    float al = sqrtf(2.83f / fmaxf(cm, 1e-8f));    // fp16 dynamic-range balancing
    float eT = expf(lr * (float)TCH);
    aR[i] = ar; aI[i] = ai;
    cbR[i] = cr; cbI[i] = ci;
    aTR[i] = eT * cosf(li * (float)TCH);
    aTI[i] = eT * sinf(li * (float)TCH);
    alp[i] = al; ralp[i] = 1.f / al;
}

__global__ __launch_bounds__(256) void s5_k0b(const float* __restrict__ Bre, const float* __restrict__ Bim,
                                              const float* __restrict__ Cre, const float* __restrict__ Cim,
                                              const float* __restrict__ W1, const float* __restrict__ W2,
                                              const float* __restrict__ b1, const float* __restrict__ b2,
                                              const float* __restrict__ Wout,
                                              const float* __restrict__ cbR, const float* __restrict__ cbI,
                                              const float* __restrict__ alp, const float* __restrict__ ralp,
                                              _Float16* Wbu, _Float16* Wc, _Float16* Wglu,
                                              _Float16* WoutT, float* bglu) {
    int stride = gridDim.x * blockDim.x;
    int tid0 = blockIdx.x * blockDim.x + threadIdx.x;
    // Wbu_t[l][n][k]: rows permuted so each k3 thread holds (re,im) of one
    // channel in adjacent nt-fragments (see k3 epilogue).
    for (int i = tid0; i < 262144; i += stride) {
        int l = i >> 16, n = (i >> 8) & 255, k = i & 255;
        int s = n >> 4, lmn = n & 15;
        int p = l * 128 + (s >> 1) * 16 + lmn;
        float re = cbR[p] * Bre[p * 256 + k] - cbI[p] * Bim[p * 256 + k];
        float im = cbR[p] * Bim[p * 256 + k] + cbI[p] * Bre[p * 256 + k];
        Wbu[i] = (_Float16)(((s & 1) ? im : re) * alp[p]);
    }
    // Wc_t[l][n][k]: k-axis interleaved to match xs: k=2p -> 2*Cre[n][p],
    // k=2p+1 -> -2*Cim[n][p]; scaled by 1/alpha[p]
    for (int i = tid0; i < 262144; i += stride) {
        int l = i >> 16, n = (i >> 8) & 255, k = i & 255;
        int p = k >> 1;
        float base = (k & 1) ? -2.f * Cim[(l * 256 + n) * 128 + p]
                             : 2.f * Cre[(l * 256 + n) * 128 + p];
        Wc[i] = (_Float16)(base * ralp[l * 128 + p]);
    }
    // Wglu_t[l][n][k]: columns permuted so GLU pairs land in the SAME thread.
    for (int i = tid0; i < 524288; i += stride) {
        int l = i >> 17, n = (i >> 8) & 511, k = i & 255;
        int j = ((n >> 7) << 6) | (((n >> 6) & 1) << 5) | (((n >> 5) & 1) << 4) | (n & 15);
        const float* src = ((n >> 4) & 1) ? W2 : W1;
        Wglu[i] = (_Float16)src[(l * 256 + k) * 256 + j];
    }
    for (int i = tid0; i < 16384; i += stride) {
        int n = i >> 8, k = i & 255;
        WoutT[i] = (_Float16)Wout[k * 64 + n];
    }
    for (int i = tid0; i < 2048; i += stride) {
        int l = i >> 9, n = i & 511;
        int j = ((n >> 7) << 6) | (((n >> 6) & 1) << 5) | (((n >> 5) & 1) << 4) | (n & 15);
        bglu[i] = (((n >> 4) & 1) ? b2 : b1)[l * 256 + j];
    }
}

__global__ __launch_bounds__(256) void s5_k0c(const float* __restrict__ latent, const float* __restrict__ W,
                                              const float* __restrict__ b, _Float16* __restrict__ x0h) {
    __shared__ float lat[256];
    lat[threadIdx.x] = latent[threadIdx.x];
    __syncthreads();
    float s = b[threadIdx.x];
    for (int k = 0; k < 256; ++k) s += lat[k] * W[k * 256 + threadIdx.x];
    x0h[threadIdx.x] = (_Float16)((s > 0.f) ? s : 0.01f * s);   // leaky_relu
}

__global__ __launch_bounds__(256) void s5_k1_fill(const _Float16* __restrict__ x0h, _Float16* __restrict__ x) {
    int i = blockIdx.x * 256 + threadIdx.x;       // 4096 blocks: L*256/8 half8s
    half8 v = *(const half8*)(x0h + (i & 31) * 8);
    *(half8*)(x + i * 8) = v;
}

// --------------------------- per-layer kernels -----------------------------
// k3 v9 (round-18 known-good): fused LN + GEMM + carry scan.
__global__ __launch_bounds__(512, 1) void s5_k3_lngemm(const _Float16* __restrict__ x,
                                                       const _Float16* __restrict__ Wt,
                                                       const float* __restrict__ gamma,
                                                       const float* __restrict__ beta,
                                                       const float* __restrict__ aR,
                                                       const float* __restrict__ aI,
                                                       _Float16* __restrict__ h,
                                                       _Float16* __restrict__ Buh,
                                                       float* __restrict__ carRI) {
    __shared__ _Float16 sW[64 * 512];        // one col-half: 64KB
    __shared__ _Float16 BuT[128 * 256];      // Bu tile, swizzled: 64KB
    int tid = threadIdx.x, wid = tid >> 6, lane = tid & 63;
    int lm = lane & 15, quad = lane >> 4;
    int m0 = blockIdx.x * 128;
    int rowb = m0 + wid * 16;

    auto stageW = [&](int half) {
#pragma unroll
        for (int i = 0; i < 8; ++i) {
            int c = i * 8 + wid;
            int ks = c >> 3, n16 = c & 7;
            gll16(Wt + (half * 128 + n16 * 16 + lm) * 256 + ks * 32 + quad * 8, sW + c * 512);
        }
    };
    stageW(0);                                // latency hides under LN below

    int row = rowb + lm;
    half8 af[8];
    {
        half8 xv[8];
#pragma unroll
        for (int ks = 0; ks < 8; ++ks)
            xv[ks] = *(const half8*)(x + row * 256 + ks * 32 + quad * 8);
        float s1 = 0.f, s2 = 0.f;
#pragma unroll
        for (int i = 0; i < 8; ++i)
#pragma unroll
            for (int j = 0; j < 8; ++j) { float t = (float)xv[i][j]; s1 += t; s2 += t * t; }
        s1 += __shfl_xor(s1, 16, 64); s2 += __shfl_xor(s2, 16, 64);
        s1 += __shfl_xor(s1, 32, 64); s2 += __shfl_xor(s2, 32, 64);
        float mu = s1 * (1.f / 256.f);
        float var = s2 * (1.f / 256.f) - mu * mu;
        float rs = rsqrtf(fmaxf(var, 0.f) + 1e-6f);
#pragma unroll
        for (int ks = 0; ks < 8; ++ks) {
            f32x4 g0 = *(const f32x4*)(gamma + ks * 32 + quad * 8);
            f32x4 g1 = *(const f32x4*)(gamma + ks * 32 + quad * 8 + 4);
            f32x4 b0 = *(const f32x4*)(beta + ks * 32 + quad * 8);
            f32x4 b1 = *(const f32x4*)(beta + ks * 32 + quad * 8 + 4);
            half8 o;
#pragma unroll
            for (int j = 0; j < 4; ++j) {
                o[j]     = (_Float16)(((float)xv[ks][j] - mu) * rs * g0[j] + b0[j]);
                o[j + 4] = (_Float16)(((float)xv[ks][j + 4] - mu) * rs * g1[j] + b1[j]);
            }
            af[ks] = o;
            *(half8*)(h + row * 256 + ks * 32 + quad * 8) = o;   // read by mega (later kernel)
        }
    }
    asm volatile("s_waitcnt vmcnt(0)" ::: "memory");   // sW half 0 staged
    __syncthreads();

    f32x4 zero = {0.f, 0.f, 0.f, 0.f};
    f32x4 acc[2][8];
#pragma unroll
    for (int hf = 0; hf < 2; ++hf)
#pragma unroll
        for (int nt = 0; nt < 8; ++nt) acc[hf][nt] = zero;

#pragma unroll
    for (int ks = 0; ks < 8; ++ks) {
        half8 bf[8];
#pragma unroll
        for (int nt = 0; nt < 8; ++nt)
            bf[nt] = *(const half8*)(sW + (ks * 8 + nt) * 512 + lane * 8);
#pragma unroll
        for (int nt = 0; nt < 8; ++nt)
            acc[0][nt] = __builtin_amdgcn_mfma_f32_16x16x32_f16(af[ks], bf[nt], acc[0][nt], 0, 0, 0);
    }
    __syncthreads();                  // all waves done reading sW half 0
    stageW(1);
    asm volatile("s_waitcnt vmcnt(0)" ::: "memory");
    __syncthreads();
#pragma unroll
    for (int ks = 0; ks < 8; ++ks) {
        half8 bf[8];
#pragma unroll
        for (int nt = 0; nt < 8; ++nt)
            bf[nt] = *(const half8*)(sW + (ks * 8 + nt) * 512 + lane * 8);
#pragma unroll
        for (int nt = 0; nt < 8; ++nt)
            acc[1][nt] = __builtin_amdgcn_mfma_f32_16x16x32_f16(af[ks], bf[nt], acc[1][nt], 0, 0, 0);
    }

    // epilogue: pair (s=2u, 2u+1) in-thread = (re,im) of channel p=u*16+lm.
    // Write Bu to global (for mega) AND to the swizzled BuT tile (for carry).
#pragma unroll
    for (int u = 0; u < 8; ++u) {
        int hf = u >> 2, q = u & 3;
        int p = u * 16 + lm;
#pragma unroll
        for (int r = 0; r < 4; ++r) {
            half2v o = {(_Float16)acc[hf][2 * q][r], (_Float16)acc[hf][2 * q + 1][r]};
            int rg = wid * 16 + quad * 4 + r;     // local row
            *(half2v*)(Buh + (m0 + rg) * 256 + 2 * p) = o;
            int byte = (4 * p) ^ ((rg & 7) << 4);
            *(half2v*)((char*)BuT + rg * 512 + byte) = o;
        }
    }
    __syncthreads();                  // BuT visible

    // ---- fused carry scan (threads 0-255: cc = chunk-in-block, p = channel)
    if (tid < 256) {
        int cc = tid >> 7, p = tid & 127;
        half2v hv[TCH];
#pragma unroll
        for (int j = 0; j < TCH; ++j) {
            int rl = cc * TCH + j;
            hv[j] = *(const half2v*)((const char*)BuT + rl * 512 + ((4 * p) ^ ((rl & 7) << 4)));
        }
        float ar = aR[p], ai = aI[p];
        float sr = 0.f, si = 0.f;
#pragma unroll
        for (int j = 0; j < TCH; ++j) {
            float nr = fmaf(ar, sr, fmaf(-ai, si, (float)hv[j][0]));
            float ni = fmaf(ar, si, fmaf(ai, sr, (float)hv[j][1]));
            sr = nr; si = ni;
        }
        *(f32x2*)(carRI + ((blockIdx.x * 2 + cc) * 128 + p) * 2) = f32x2{sr, si};
    }
}

// k7 v7 "mega": as v6 plus (a) h routed through LDS -- coalesced half8 global
// loads overlapped with the Wc-half-1 staging, written into xsT (dead after
// A-fragment extraction) with the g-style swizzle; the h*D term reads fp16
// from LDS instead of 64 scalar global loads/thread. (b) GLU xold loads all
// hoisted to issue together after bar4 (deep MLP). Same values, same order ->
// identical numerics to v6.
__global__ __launch_bounds__(512, 1) void s5_k7_mega(const _Float16* __restrict__ Bu,
                                                     const float* __restrict__ carRI,
                                                     const _Float16* __restrict__ Wc,
                                                     const _Float16* __restrict__ Wglu,
                                                     const _Float16* __restrict__ h,
                                                     const float* __restrict__ aR, const float* __restrict__ aI,
                                                     const float* __restrict__ aTR, const float* __restrict__ aTI,
                                                     const float* __restrict__ Dv,
                                                     const float* __restrict__ gamma,
                                                     const float* __restrict__ beta,
                                                     const float* __restrict__ bias,
                                                     _Float16* __restrict__ x) {
    __shared__ _Float16 sW[64 * 512];        // Wc col-half / Wglu col-chunk: 64KB
    __shared__ _Float16 xsT[128 * 256];      // xs states -> h tile -> g tile; swizzled: 64KB
    int tid = threadIdx.x, wid = tid >> 6, lane = tid & 63;
    int lm = lane & 15, quad = lane >> 4;
    int m0 = blockIdx.x * 128;
    int rowb = m0 + wid * 16;

    auto stageWc = [&](int half) {
#pragma unroll
        for (int i = 0; i < 8; ++i) {
            int c = i * 8 + wid;
            int ks = c >> 3, n16 = c & 7;
            gll16(Wc + (half * 128 + n16 * 16 + lm) * 256 + ks * 32 + quad * 8, sW + c * 512);
        }
    };
    auto stageWg = [&](int n0) {
#pragma unroll
        for (int i = 0; i < 8; ++i) {
            int c = i * 8 + wid;
            int ks = c >> 3, n16 = c & 7;
            gll16(Wglu + (n0 + n16 * 16 + lm) * 256 + ks * 32 + quad * 8, sW + c * 512);
        }
    };
    stageWc(0);

    // ---- fused scan (threads 0-255: cc = chunk-in-block, p = channel) ----
    if (tid < 256) {
        int cc = tid >> 7, p = tid & 127;
        int cg = blockIdx.x * 2 + cc;             // global chunk id
        const _Float16* bp = Bu + (m0 + cc * TCH) * 256 + 2 * p;
        half2v hv[TCH];
#pragma unroll
        for (int j = 0; j < TCH; ++j) hv[j] = *(const half2v*)(bp + j * 256);
        float tr = aTR[p], ti = aTI[p];
        float cr = 0.f, ci = 0.f;
#pragma unroll 8
        for (int i = 0; i < cg; ++i) {            // exclusive prefix (L2-resident)
            f32x2 w = *(const f32x2*)(carRI + (i * 128 + p) * 2);
            float nr = fmaf(tr, cr, fmaf(-ti, ci, w[0]));
            float ni = fmaf(tr, ci, fmaf(ti, cr, w[1]));
            cr = nr; ci = ni;
        }
        float ar = aR[p], ai = aI[p];
        float sr = cr, si = ci;                   // s_{-1} = carry
#pragma unroll
        for (int j = 0; j < TCH; ++j) {
            float nr = fmaf(ar, sr, fmaf(-ai, si, (float)hv[j][0]));
            float ni = fmaf(ar, si, fmaf(ai, sr, (float)hv[j][1]));
            sr = nr; si = ni;
            int rl = cc * TCH + j;
            int byte = (4 * p) ^ ((rl & 7) << 4);     // XOR swizzle (write side)
            *(half2v*)((char*)xsT + rl * 512 + byte) = half2v{(_Float16)sr, (_Float16)si};
        }
    }
    asm volatile("s_waitcnt vmcnt(0)" ::: "memory");   // sW(Wc,0) + Bu loads done
    __syncthreads();                                    // bar1: xsT + sW ready

    // A-fragments from swizzled LDS (read side XOR matches write side)
    int rl = wid * 16 + lm;                       // row_local of this lane's row
    half8 af[8];
#pragma unroll
    for (int ks = 0; ks < 8; ++ks) {
        int b = ks * 64 + quad * 16;
        af[ks] = *(const half8*)((const char*)xsT + rl * 512 + (b ^ ((rl & 7) << 4)));
    }

    f32x4 zero = {0.f, 0.f, 0.f, 0.f};
    f32x4 acc[2][8];
#pragma unroll
    for (int hf = 0; hf < 2; ++hf)
#pragma unroll
        for (int nt = 0; nt < 8; ++nt) acc[hf][nt] = zero;

#pragma unroll
    for (int ks = 0; ks < 8; ++ks) {
        half8 bf[8];
#pragma unroll
        for (int nt = 0; nt < 8; ++nt)
            bf[nt] = *(const half8*)(sW + (ks * 8 + nt) * 512 + lane * 8);
#pragma unroll
        for (int nt = 0; nt < 8; ++nt)
            acc[0][nt] = __builtin_amdgcn_mfma_f32_16x16x32_f16(af[ks], bf[nt], acc[0][nt], 0, 0, 0);
    }
    __syncthreads();                  // bar2: all waves done reading sW(Wc,0); xsT dead
    stageWc(1);
    // coalesced h load (deep MLP) -- overlaps the Wc-half-1 staging latency
    half8 hv8[8];
#pragma unroll
    for (int ks = 0; ks < 8; ++ks)
        hv8[ks] = *(const half8*)(h + (rowb + lm) * 256 + ks * 32 + quad * 8);
    asm volatile("s_waitcnt vmcnt(0)" ::: "memory");   // sW(Wc,1) + h loads done
    // write h into xsT (g-style fp16 swizzled layout)
#pragma unroll
    for (int ks = 0; ks < 8; ++ks) {
        int b = (ks * 64 + quad * 16) ^ ((rl & 7) << 4);
        *(half8*)((char*)xsT + rl * 512 + b) = hv8[ks];
    }
    __syncthreads();                  // bar3: sW(Wc,1) + hT ready
#pragma unroll
    for (int ks = 0; ks < 8; ++ks) {
        half8 bf[8];
#pragma unroll
        for (int nt = 0; nt < 8; ++nt)
            bf[nt] = *(const half8*)(sW + (ks * 8 + nt) * 512 + lane * 8);
#pragma unroll
        for (int nt = 0; nt < 8; ++nt)
            acc[1][nt] = __builtin_amdgcn_mfma_f32_16x16x32_f16(af[ks], bf[nt], acc[1][nt], 0, 0, 0);
    }

    // y = xs@Wc + h*D  (h from swizzled LDS)
#pragma unroll
    for (int hf = 0; hf < 2; ++hf)
#pragma unroll
        for (int nt = 0; nt < 8; ++nt) {
            int col = hf * 128 + nt * 16 + lm;
            float dv = Dv[col];
#pragma unroll
            for (int r = 0; r < 4; ++r) {
                int rg = wid * 16 + quad * 4 + r;
                float hvv = (float)*((const _Float16*)((const char*)xsT + rg * 512 +
                                                       ((2 * col) ^ ((rg & 7) << 4))));
                acc[hf][nt][r] += hvv * dv;
            }
        }
    // wave-local LN
    float mu[4], rs[4];
#pragma unroll
    for (int r = 0; r < 4; ++r) {
        float a = 0.f, b = 0.f;
#pragma unroll
        for (int hf = 0; hf < 2; ++hf)
#pragma unroll
            for (int nt = 0; nt < 8; ++nt) {
                float v = acc[hf][nt][r];
                a += v; b += v * v;
            }
#pragma unroll
        for (int off = 1; off < 16; off <<= 1) {
            a += __shfl_xor(a, off, 64);
            b += __shfl_xor(b, off, 64);
        }
        float m = a * (1.f / 256.f);
        float var = b * (1.f / 256.f) - m * m;
        mu[r] = m;
        rs[r] = rsqrtf(fmaxf(var, 0.f) + 1e-6f);
    }
    // gelu -> g written fp16 into xsT (per-wave slice: h reads done in-wave first)
#pragma unroll
    for (int hf = 0; hf < 2; ++hf)
#pragma unroll
        for (int nt = 0; nt < 8; ++nt) {
            int col = hf * 128 + nt * 16 + lm;
            float ga = gamma[col], be = beta[col];
#pragma unroll
            for (int r = 0; r < 4; ++r) {
                float hn = (acc[hf][nt][r] - mu[r]) * rs[r] * ga + be;
                int rg = wid * 16 + quad * 4 + r;
                int byte = (2 * col) ^ ((rg & 7) << 4);
                *((_Float16*)((char*)xsT + rg * 512 + byte)) = (_Float16)gelu_(hn);
            }
        }
    __syncthreads();                  // bar4: g visible; all sW(Wc) reads done
    stageWg(0);
    // g A-fragments (xsT, swizzled) -- overlaps the Wglu staging latency
    half8 ag[8];
#pragma unroll
    for (int ks = 0; ks < 8; ++ks) {
        int b = ks * 64 + quad * 16;
        ag[ks] = *(const half8*)((const char*)xsT + rl * 512 + (b ^ ((rl & 7) << 4)));
    }
    // hoist ALL GLU xold loads (64 x 2B, deep MLP; static indices)
    _Float16 xold[4][4][4];
#pragma unroll
    for (int cy = 0; cy < 4; ++cy)
#pragma unroll
        for (int q = 0; q < 4; ++q)
#pragma unroll
            for (int r = 0; r < 4; ++r)
                xold[cy][q][r] = x[(rowb + quad * 4 + r) * 256 + cy * 64 + lm + q * 16];
    asm volatile("s_waitcnt vmcnt(0)" ::: "memory");
    __syncthreads();                  // bar5: sW(Wglu,0) ready

#pragma unroll
    for (int cy = 0; cy < 4; ++cy) {
        f32x4 accg[8];
#pragma unroll
        for (int nt = 0; nt < 8; ++nt) accg[nt] = zero;
#pragma unroll
        for (int ks = 0; ks < 8; ++ks) {
            half8 bf[8];
#pragma unroll
            for (int nt = 0; nt < 8; ++nt)
                bf[nt] = *(const half8*)(sW + (ks * 8 + nt) * 512 + lane * 8);
#pragma unroll
            for (int nt = 0; nt < 8; ++nt)
                accg[nt] = __builtin_amdgcn_mfma_f32_16x16x32_f16(ag[ks], bf[nt], accg[nt], 0, 0, 0);
        }
        // GLU epilogue for n0 = cy*128 (pairs in-thread via Wglu permutation)
        int n0 = cy * 128;
        int jbase = (n0 >> 1) + lm;
#pragma unroll
        for (int q = 0; q < 4; ++q) {
            float b1v = bias[n0 + (2 * q) * 16 + lm];
            float b2v = bias[n0 + (2 * q + 1) * 16 + lm];
            int jcol = jbase + q * 16;
#pragma unroll
            for (int r = 0; r < 4; ++r) {
                float u1 = accg[2 * q][r] + b1v;
                float u2 = accg[2 * q + 1][r] + b2v;
                float gl = u1 * sigmoidf_(u2);
                int idx = (rowb + quad * 4 + r) * 256 + jcol;
                x[idx] = (_Float16)((float)xold[cy][q][r] + gl);   // fp16 residual
            }
        }
        if (cy < 3) {
            __syncthreads();          // all waves done reading sW(Wglu,cy)
            stageWg((cy + 1) * 128);
            asm volatile("s_waitcnt vmcnt(0)" ::: "memory");
            __syncthreads();
        }
    }
}

// k9 v2: deep-MLP streaming GEMM for the output projection.
__global__ __launch_bounds__(256, 2) void s5_k9_gemm_out(const _Float16* __restrict__ A,
                                                         const _Float16* __restrict__ Wt,
                                                         const float* __restrict__ bout,
                                                         float* __restrict__ out) {
    __shared__ _Float16 sW[32 * 512];        // chunk c = ks*4 + n16
    int tid = threadIdx.x, wid = tid >> 6, lane = tid & 63;
    int lm = lane & 15, quad = lane >> 4;
    int m0 = blockIdx.x * 128;
#pragma unroll
    for (int i = 0; i < 8; ++i) {
        int c = i * 4 + wid;
        int ks = c >> 2, n16 = c & 3;
        gll16(Wt + (n16 * 16 + lm) * 256 + ks * 32 + quad * 8, sW + c * 512);
    }
    int rowb = m0 + wid * 32;
    half8 af[2][8];
#pragma unroll
    for (int mt = 0; mt < 2; ++mt)
#pragma unroll
        for (int ks = 0; ks < 8; ++ks)
            af[mt][ks] = *(const half8*)(A + (rowb + mt * 16 + lm) * 256 + ks * 32 + quad * 8);
    asm volatile("s_waitcnt vmcnt(0)" ::: "memory");
    __syncthreads();

    f32x4 zero = {0.f, 0.f, 0.f, 0.f};
    f32x4 acc[2][4];
#pragma unroll
    for (int mt = 0; mt < 2; ++mt)
#pragma unroll
        for (int nt = 0; nt < 4; ++nt) acc[mt][nt] = zero;
#pragma unroll
    for (int ks = 0; ks < 8; ++ks) {
        half8 bf[4];
#pragma unroll
        for (int nt = 0; nt < 4; ++nt)
            bf[nt] = *(const half8*)(sW + (ks * 4 + nt) * 512 + lane * 8);
#pragma unroll
        for (int mt = 0; mt < 2; ++mt)
#pragma unroll
            for (int nt = 0; nt < 4; ++nt)
                acc[mt][nt] = __builtin_amdgcn_mfma_f32_16x16x32_f16(af[mt][ks], bf[nt], acc[mt][nt], 0, 0, 0);
    }
#pragma unroll
    for (int mt = 0; mt < 2; ++mt)
#pragma unroll
        for (int nt = 0; nt < 4; ++nt) {
            int col = nt * 16 + lm;
            float bv = bout[col];
#pragma unroll
            for (int r = 0; r < 4; ++r) {
                int row = rowb + mt * 16 + quad * 4 + r;
                out[row * 64 + col] = acc[mt][nt][r] + bv;
            }
        }
}

// --------------------------- workspace layout ------------------------------
constexpr size_t OFF_X    = 0;                         // half L*256 residual x  16.8MB
constexpr size_t OFF_BU   = 33554432;                  // half L*256 Bu
constexpr size_t OFF_H    = 67108864;                  // half L*256 (h)
constexpr size_t OFF_WBU  = 100663296;                 // half 4*256*256
constexpr size_t OFF_WC   = OFF_WBU + 524288;
constexpr size_t OFF_WGLU = OFF_WC + 524288;           // half 4*512*256
constexpr size_t OFF_WOUT = OFF_WGLU + 1048576;        // half 64*256
constexpr size_t OFF_BGLU = OFF_WOUT + 32768;          // f32 4*512
constexpr size_t OFF_AR   = OFF_BGLU + 8192;
constexpr size_t OFF_AI   = OFF_AR + 2048;
constexpr size_t OFF_CBR  = OFF_AI + 2048;
constexpr size_t OFF_CBI  = OFF_CBR + 2048;
constexpr size_t OFF_ATR  = OFF_CBI + 2048;
constexpr size_t OFF_ATI  = OFF_ATR + 2048;
constexpr size_t OFF_ALP  = OFF_ATI + 2048;
constexpr size_t OFF_RALP = OFF_ALP + 2048;
constexpr size_t OFF_X0H  = OFF_RALP + 2048;           // half 256
constexpr size_t OFF_CARRI= OFF_X0H + 1024;            // f32x2 NCH*128 (512KB)

extern "C" void kernel_launch(void* const* d_in, const int* in_sizes, int n_in,
                              void* d_out, int out_size, void* d_ws, size_t ws_size,
                              hipStream_t stream) {
    (void)in_sizes; (void)n_in; (void)out_size; (void)ws_size;
    const float* latent    = (const float*)d_in[0];
    const float* W_expand  = (const float*)d_in[1];
    const float* b_expand  = (const float*)d_in[2];
    const float* norm_s    = (const float*)d_in[3];
    const float* norm_b    = (const float*)d_in[4];
    const float* Lre       = (const float*)d_in[5];
    const float* Lim       = (const float*)d_in[6];
    const float* Bre       = (const float*)d_in[7];
    const float* Bim       = (const float*)d_in[8];
    const float* Cre       = (const float*)d_in[9];
    const float* Cim       = (const float*)d_in[10];
    const float* Dv        = (const float*)d_in[11];
    const float* lstep     = (const float*)d_in[12];
    const float* W1        = (const float*)d_in[13];
    const float* b1        = (const float*)d_in[14];
    const float* W2        = (const float*)d_in[15];
    const float* b2        = (const float*)d_in[16];
    const float* Wout      = (const float*)d_in[17];
    const float* bout      = (const float*)d_in[18];

    char* ws = (char*)d_ws;
    _Float16* x    = (_Float16*)(ws + OFF_X);
    _Float16* Buh  = (_Float16*)(ws + OFF_BU);                 // fp16 Bu (16.8MB)
    _Float16* hbuf = (_Float16*)(ws + OFF_H);
    _Float16* Wbu  = (_Float16*)(ws + OFF_WBU);
    _Float16* Wc   = (_Float16*)(ws + OFF_WC);
    _Float16* Wglu = (_Float16*)(ws + OFF_WGLU);
    _Float16* WoutT= (_Float16*)(ws + OFF_WOUT);
    float* bglu = (float*)(ws + OFF_BGLU);
    float* aR  = (float*)(ws + OFF_AR);
    float* aI  = (float*)(ws + OFF_AI);
    float* cbR = (float*)(ws + OFF_CBR);
    float* cbI = (float*)(ws + OFF_CBI);
    float* aTR = (float*)(ws + OFF_ATR);
    float* aTI = (float*)(ws + OFF_ATI);
    float* alp = (float*)(ws + OFF_ALP);
    float* ralp= (float*)(ws + OFF_RALP);
    _Float16* x0h = (_Float16*)(ws + OFF_X0H);
    float* carRI=(float*)(ws + OFF_CARRI);

    s5_k0a<<<1, 512, 0, stream>>>(Lre, Lim, lstep, aR, aI, cbR, cbI, aTR, aTI, alp, ralp);
    s5_k0b<<<256, 256, 0, stream>>>(Bre, Bim, Cre, Cim, W1, W2, b1, b2, Wout,
                                    cbR, cbI, alp, ralp, Wbu, Wc, Wglu, WoutT, bglu);
    s5_k0c<<<1, 256, 0, stream>>>(latent, W_expand, b_expand, x0h);
    s5_k1_fill<<<4096, 256, 0, stream>>>(x0h, x);

    for (int l = 0; l < 4; ++l) {
        s5_k3_lngemm<<<256, 512, 0, stream>>>(x, Wbu + l * 65536,
                                              norm_s + l * 256, norm_b + l * 256,
                                              aR + l * 128, aI + l * 128,
                                              hbuf, Buh, carRI);
        s5_k7_mega<<<256, 512, 0, stream>>>(Buh, carRI, Wc + l * 65536, Wglu + l * 131072,
                                            hbuf,
                                            aR + l * 128, aI + l * 128,
                                            aTR + l * 128, aTI + l * 128,
                                            Dv + l * 256,
                                            norm_s + l * 256, norm_b + l * 256,
                                            bglu + l * 512, x);
    }
    s5_k9_gemm_out<<<256, 256, 0, stream>>>(x, WoutT, bout, (float*)d_out);
}

// Round 20
// 449.356 us; speedup vs baseline: 1.0250x; 1.0250x over previous
//
#include <hip/hip_runtime.h>
#include <stdint.h>

#define LSEQ 32768
#define NCH 512      // scan chunks
#define TCH 64       // timesteps per chunk  (NCH*TCH == LSEQ)

typedef _Float16 half8 __attribute__((ext_vector_type(8)));
typedef _Float16 half4v __attribute__((ext_vector_type(4)));
typedef _Float16 half2v __attribute__((ext_vector_type(2)));
typedef float f32x4 __attribute__((ext_vector_type(4)));
typedef float f32x2 __attribute__((ext_vector_type(2)));

__device__ __forceinline__ float sigmoidf_(float x) { return 1.f / (1.f + __expf(-x)); }
__device__ __forceinline__ float gelu_(float x) {
    float z = 0.7978845608028654f * (x + 0.044715f * x * x * x);
    float e = __expf(2.f * z);
    float t = 1.f - 2.f / (e + 1.f);   // tanh(z)
    return 0.5f * x * (1.f + t);
}

// async global->LDS, 16B per lane. LDS dest is wave-uniform base; HW writes
// base + lane*16 (matches the fragment-major chunk layout below).
__device__ __forceinline__ void gll16(const _Float16* gp, _Float16* lp) {
    __builtin_amdgcn_global_load_lds((__attribute__((address_space(1))) void*)gp,
                                     (__attribute__((address_space(3))) void*)lp, 16, 0, 0);
}

// --------------------------- setup kernels ---------------------------------
__global__ __launch_bounds__(512) void s5_k0a(const float* __restrict__ lre, const float* __restrict__ lim,
                                              const float* __restrict__ lstep,
                                              float* aR, float* aI, float* cbR, float* cbI,
                                              float* aTR, float* aTI, float* alp, float* ralp) {
    int i = threadIdx.x;  // 4 layers * 128 channels
    float st = expf(lstep[i]);
    float lr = lre[i] * st, li = lim[i] * st;
    float ea = expf(lr);
    float ar = ea * cosf(li), ai = ea * sinf(li);
    float den = lre[i] * lre[i] + lim[i] * lim[i];
    float nr = ar - 1.f, ni = ai;
    float cr = (nr * lre[i] + ni * lim[i]) / den;   // (a-1)/Lambda
    float ci = (ni * lre[i] - nr * lim[i]) / den;
    float cm = sqrtf(cr * cr + ci * ci);
    float al = sqrtf(2.83f / fmaxf(cm, 1e-8f));    // fp16 dynamic-range balancing
    float eT = expf(lr * (float)TCH);
    aR[i] = ar; aI[i] = ai;
    cbR[i] = cr; cbI[i] = ci;
    aTR[i] = eT * cosf(li * (float)TCH);
    aTI[i] = eT * sinf(li * (float)TCH);
    alp[i] = al; ralp[i] = 1.f / al;
}

__global__ __launch_bounds__(256) void s5_k0b(const float* __restrict__ Bre, const float* __restrict__ Bim,
                                              const float* __restrict__ Cre, const float* __restrict__ Cim,
                                              const float* __restrict__ W1, const float* __restrict__ W2,
                                              const float* __restrict__ b1, const float* __restrict__ b2,
                                              const float* __restrict__ Wout,
                                              const float* __restrict__ cbR, const float* __restrict__ cbI,
                                              const float* __restrict__ alp, const float* __restrict__ ralp,
                                              _Float16* Wbu, _Float16* Wc, _Float16* Wglu,
                                              _Float16* WoutT, float* bglu) {
    int stride = gridDim.x * blockDim.x;
    int tid0 = blockIdx.x * blockDim.x + threadIdx.x;
    // Wbu_t[l][n][k]: rows permuted so each k3 thread holds (re,im) of one
    // channel in adjacent nt-fragments (see k3 epilogue).
    for (int i = tid0; i < 262144; i += stride) {
        int l = i >> 16, n = (i >> 8) & 255, k = i & 255;
        int s = n >> 4, lmn = n & 15;
        int p = l * 128 + (s >> 1) * 16 + lmn;
        float re = cbR[p] * Bre[p * 256 + k] - cbI[p] * Bim[p * 256 + k];
        float im = cbR[p] * Bim[p * 256 + k] + cbI[p] * Bre[p * 256 + k];
        Wbu[i] = (_Float16)(((s & 1) ? im : re) * alp[p]);
    }
    // Wc_t[l][n][k]: k-axis interleaved to match xs: k=2p -> 2*Cre[n][p],
    // k=2p+1 -> -2*Cim[n][p]; scaled by 1/alpha[p]
    for (int i = tid0; i < 262144; i += stride) {
        int l = i >> 16, n = (i >> 8) & 255, k = i & 255;
        int p = k >> 1;
        float base = (k & 1) ? -2.f * Cim[(l * 256 + n) * 128 + p]
                             : 2.f * Cre[(l * 256 + n) * 128 + p];
        Wc[i] = (_Float16)(base * ralp[l * 128 + p]);
    }
    // Wglu_t[l][n][k]: columns permuted so GLU pairs land in the SAME thread.
    for (int i = tid0; i < 524288; i += stride) {
        int l = i >> 17, n = (i >> 8) & 511, k = i & 255;
        int j = ((n >> 7) << 6) | (((n >> 6) & 1) << 5) | (((n >> 5) & 1) << 4) | (n & 15);
        const float* src = ((n >> 4) & 1) ? W2 : W1;
        Wglu[i] = (_Float16)src[(l * 256 + k) * 256 + j];
    }
    for (int i = tid0; i < 16384; i += stride) {
        int n = i >> 8, k = i & 255;
        WoutT[i] = (_Float16)Wout[k * 64 + n];
    }
    for (int i = tid0; i < 2048; i += stride) {
        int l = i >> 9, n = i & 511;
        int j = ((n >> 7) << 6) | (((n >> 6) & 1) << 5) | (((n >> 5) & 1) << 4) | (n & 15);
        bglu[i] = (((n >> 4) & 1) ? b2 : b1)[l * 256 + j];
    }
}

__global__ __launch_bounds__(256) void s5_k0c(const float* __restrict__ latent, const float* __restrict__ W,
                                              const float* __restrict__ b, _Float16* __restrict__ x0h) {
    __shared__ float lat[256];
    lat[threadIdx.x] = latent[threadIdx.x];
    __syncthreads();
    float s = b[threadIdx.x];
    for (int k = 0; k < 256; ++k) s += lat[k] * W[k * 256 + threadIdx.x];
    x0h[threadIdx.x] = (_Float16)((s > 0.f) ? s : 0.01f * s);   // leaky_relu
}

__global__ __launch_bounds__(256) void s5_k1_fill(const _Float16* __restrict__ x0h, _Float16* __restrict__ x) {
    int i = blockIdx.x * 256 + threadIdx.x;       // 4096 blocks: L*256/8 half8s
    half8 v = *(const half8*)(x0h + (i & 31) * 8);
    *(half8*)(x + i * 8) = v;
}

// --------------------------- per-layer kernels -----------------------------
// k3 v9 (round-18 known-good): fused LN + GEMM + carry scan.
__global__ __launch_bounds__(512, 1) void s5_k3_lngemm(const _Float16* __restrict__ x,
                                                       const _Float16* __restrict__ Wt,
                                                       const float* __restrict__ gamma,
                                                       const float* __restrict__ beta,
                                                       const float* __restrict__ aR,
                                                       const float* __restrict__ aI,
                                                       _Float16* __restrict__ h,
                                                       _Float16* __restrict__ Buh,
                                                       float* __restrict__ carRI) {
    __shared__ _Float16 sW[64 * 512];        // one col-half: 64KB
    __shared__ _Float16 BuT[128 * 256];      // Bu tile, swizzled: 64KB
    int tid = threadIdx.x, wid = tid >> 6, lane = tid & 63;
    int lm = lane & 15, quad = lane >> 4;
    int m0 = blockIdx.x * 128;
    int rowb = m0 + wid * 16;

    auto stageW = [&](int half) {
#pragma unroll
        for (int i = 0; i < 8; ++i) {
            int c = i * 8 + wid;
            int ks = c >> 3, n16 = c & 7;
            gll16(Wt + (half * 128 + n16 * 16 + lm) * 256 + ks * 32 + quad * 8, sW + c * 512);
        }
    };
    stageW(0);                                // latency hides under LN below

    int row = rowb + lm;
    half8 af[8];
    {
        half8 xv[8];
#pragma unroll
        for (int ks = 0; ks < 8; ++ks)
            xv[ks] = *(const half8*)(x + row * 256 + ks * 32 + quad * 8);
        float s1 = 0.f, s2 = 0.f;
#pragma unroll
        for (int i = 0; i < 8; ++i)
#pragma unroll
            for (int j = 0; j < 8; ++j) { float t = (float)xv[i][j]; s1 += t; s2 += t * t; }
        s1 += __shfl_xor(s1, 16, 64); s2 += __shfl_xor(s2, 16, 64);
        s1 += __shfl_xor(s1, 32, 64); s2 += __shfl_xor(s2, 32, 64);
        float mu = s1 * (1.f / 256.f);
        float var = s2 * (1.f / 256.f) - mu * mu;
        float rs = rsqrtf(fmaxf(var, 0.f) + 1e-6f);
#pragma unroll
        for (int ks = 0; ks < 8; ++ks) {
            f32x4 g0 = *(const f32x4*)(gamma + ks * 32 + quad * 8);
            f32x4 g1 = *(const f32x4*)(gamma + ks * 32 + quad * 8 + 4);
            f32x4 b0 = *(const f32x4*)(beta + ks * 32 + quad * 8);
            f32x4 b1 = *(const f32x4*)(beta + ks * 32 + quad * 8 + 4);
            half8 o;
#pragma unroll
            for (int j = 0; j < 4; ++j) {
                o[j]     = (_Float16)(((float)xv[ks][j] - mu) * rs * g0[j] + b0[j]);
                o[j + 4] = (_Float16)(((float)xv[ks][j + 4] - mu) * rs * g1[j] + b1[j]);
            }
            af[ks] = o;
            *(half8*)(h + row * 256 + ks * 32 + quad * 8) = o;   // read by mega (later kernel)
        }
    }
    asm volatile("s_waitcnt vmcnt(0)" ::: "memory");   // sW half 0 staged
    __syncthreads();

    f32x4 zero = {0.f, 0.f, 0.f, 0.f};
    f32x4 acc[2][8];
#pragma unroll
    for (int hf = 0; hf < 2; ++hf)
#pragma unroll
        for (int nt = 0; nt < 8; ++nt) acc[hf][nt] = zero;

#pragma unroll
    for (int ks = 0; ks < 8; ++ks) {
        half8 bf[8];
#pragma unroll
        for (int nt = 0; nt < 8; ++nt)
            bf[nt] = *(const half8*)(sW + (ks * 8 + nt) * 512 + lane * 8);
#pragma unroll
        for (int nt = 0; nt < 8; ++nt)
            acc[0][nt] = __builtin_amdgcn_mfma_f32_16x16x32_f16(af[ks], bf[nt], acc[0][nt], 0, 0, 0);
    }
    __syncthreads();                  // all waves done reading sW half 0
    stageW(1);
    asm volatile("s_waitcnt vmcnt(0)" ::: "memory");
    __syncthreads();
#pragma unroll
    for (int ks = 0; ks < 8; ++ks) {
        half8 bf[8];
#pragma unroll
        for (int nt = 0; nt < 8; ++nt)
            bf[nt] = *(const half8*)(sW + (ks * 8 + nt) * 512 + lane * 8);
#pragma unroll
        for (int nt = 0; nt < 8; ++nt)
            acc[1][nt] = __builtin_amdgcn_mfma_f32_16x16x32_f16(af[ks], bf[nt], acc[1][nt], 0, 0, 0);
    }

    // epilogue: pair (s=2u, 2u+1) in-thread = (re,im) of channel p=u*16+lm.
    // Write Bu to global (for mega) AND to the swizzled BuT tile (for carry).
#pragma unroll
    for (int u = 0; u < 8; ++u) {
        int hf = u >> 2, q = u & 3;
        int p = u * 16 + lm;
#pragma unroll
        for (int r = 0; r < 4; ++r) {
            half2v o = {(_Float16)acc[hf][2 * q][r], (_Float16)acc[hf][2 * q + 1][r]};
            int rg = wid * 16 + quad * 4 + r;     // local row
            *(half2v*)(Buh + (m0 + rg) * 256 + 2 * p) = o;
            int byte = (4 * p) ^ ((rg & 7) << 4);
            *(half2v*)((char*)BuT + rg * 512 + byte) = o;
        }
    }
    __syncthreads();                  // BuT visible

    // ---- fused carry scan (threads 0-255: cc = chunk-in-block, p = channel)
    if (tid < 256) {
        int cc = tid >> 7, p = tid & 127;
        half2v hv[TCH];
#pragma unroll
        for (int j = 0; j < TCH; ++j) {
            int rl = cc * TCH + j;
            hv[j] = *(const half2v*)((const char*)BuT + rl * 512 + ((4 * p) ^ ((rl & 7) << 4)));
        }
        float ar = aR[p], ai = aI[p];
        float sr = 0.f, si = 0.f;
#pragma unroll
        for (int j = 0; j < TCH; ++j) {
            float nr = fmaf(ar, sr, fmaf(-ai, si, (float)hv[j][0]));
            float ni = fmaf(ar, si, fmaf(ai, sr, (float)hv[j][1]));
            sr = nr; si = ni;
        }
        *(f32x2*)(carRI + ((blockIdx.x * 2 + cc) * 128 + p) * 2) = f32x2{sr, si};
    }
}

// k7 v6 "mega" (round-18 known-good): fused scan + GEMM-C + LN/gelu + GLU
// GEMM + residual. g never leaves LDS.
__global__ __launch_bounds__(512, 1) void s5_k7_mega(const _Float16* __restrict__ Bu,
                                                     const float* __restrict__ carRI,
                                                     const _Float16* __restrict__ Wc,
                                                     const _Float16* __restrict__ Wglu,
                                                     const _Float16* __restrict__ h,
                                                     const float* __restrict__ aR, const float* __restrict__ aI,
                                                     const float* __restrict__ aTR, const float* __restrict__ aTI,
                                                     const float* __restrict__ Dv,
                                                     const float* __restrict__ gamma,
                                                     const float* __restrict__ beta,
                                                     const float* __restrict__ bias,
                                                     _Float16* __restrict__ x) {
    __shared__ _Float16 sW[64 * 512];        // Wc col-half / Wglu col-chunk: 64KB
    __shared__ _Float16 xsT[128 * 256];      // scanned states, then g; swizzled: 64KB
    int tid = threadIdx.x, wid = tid >> 6, lane = tid & 63;
    int lm = lane & 15, quad = lane >> 4;
    int m0 = blockIdx.x * 128;
    int rowb = m0 + wid * 16;

    auto stageWc = [&](int half) {
#pragma unroll
        for (int i = 0; i < 8; ++i) {
            int c = i * 8 + wid;
            int ks = c >> 3, n16 = c & 7;
            gll16(Wc + (half * 128 + n16 * 16 + lm) * 256 + ks * 32 + quad * 8, sW + c * 512);
        }
    };
    auto stageWg = [&](int n0) {
#pragma unroll
        for (int i = 0; i < 8; ++i) {
            int c = i * 8 + wid;
            int ks = c >> 3, n16 = c & 7;
            gll16(Wglu + (n0 + n16 * 16 + lm) * 256 + ks * 32 + quad * 8, sW + c * 512);
        }
    };
    stageWc(0);

    // ---- fused scan (threads 0-255: cc = chunk-in-block, p = channel) ----
    if (tid < 256) {
        int cc = tid >> 7, p = tid & 127;
        int cg = blockIdx.x * 2 + cc;             // global chunk id
        const _Float16* bp = Bu + (m0 + cc * TCH) * 256 + 2 * p;
        half2v hv[TCH];
#pragma unroll
        for (int j = 0; j < TCH; ++j) hv[j] = *(const half2v*)(bp + j * 256);
        float tr = aTR[p], ti = aTI[p];
        float cr = 0.f, ci = 0.f;
#pragma unroll 8
        for (int i = 0; i < cg; ++i) {            // exclusive prefix (L2-resident)
            f32x2 w = *(const f32x2*)(carRI + (i * 128 + p) * 2);
            float nr = fmaf(tr, cr, fmaf(-ti, ci, w[0]));
            float ni = fmaf(tr, ci, fmaf(ti, cr, w[1]));
            cr = nr; ci = ni;
        }
        float ar = aR[p], ai = aI[p];
        float sr = cr, si = ci;                   // s_{-1} = carry
#pragma unroll
        for (int j = 0; j < TCH; ++j) {
            float nr = fmaf(ar, sr, fmaf(-ai, si, (float)hv[j][0]));
            float ni = fmaf(ar, si, fmaf(ai, sr, (float)hv[j][1]));
            sr = nr; si = ni;
            int rl = cc * TCH + j;
            int byte = (4 * p) ^ ((rl & 7) << 4);     // XOR swizzle (write side)
            *(half2v*)((char*)xsT + rl * 512 + byte) = half2v{(_Float16)sr, (_Float16)si};
        }
    }
    asm volatile("s_waitcnt vmcnt(0)" ::: "memory");   // sW(Wc,0) + Bu loads done
    __syncthreads();                                    // bar1: xsT + sW ready

    // A-fragments from swizzled LDS (read side XOR matches write side)
    int rl = wid * 16 + lm;                       // row_local of this lane's row
    half8 af[8];
#pragma unroll
    for (int ks = 0; ks < 8; ++ks) {
        int b = ks * 64 + quad * 16;
        af[ks] = *(const half8*)((const char*)xsT + rl * 512 + (b ^ ((rl & 7) << 4)));
    }

    f32x4 zero = {0.f, 0.f, 0.f, 0.f};
    f32x4 acc[2][8];
#pragma unroll
    for (int hf = 0; hf < 2; ++hf)
#pragma unroll
        for (int nt = 0; nt < 8; ++nt) acc[hf][nt] = zero;

#pragma unroll
    for (int ks = 0; ks < 8; ++ks) {
        half8 bf[8];
#pragma unroll
        for (int nt = 0; nt < 8; ++nt)
            bf[nt] = *(const half8*)(sW + (ks * 8 + nt) * 512 + lane * 8);
#pragma unroll
        for (int nt = 0; nt < 8; ++nt)
            acc[0][nt] = __builtin_amdgcn_mfma_f32_16x16x32_f16(af[ks], bf[nt], acc[0][nt], 0, 0, 0);
    }
    __syncthreads();                  // bar2: all waves done reading sW(Wc,0)
    stageWc(1);
    asm volatile("s_waitcnt vmcnt(0)" ::: "memory");
    __syncthreads();                  // bar3
#pragma unroll
    for (int ks = 0; ks < 8; ++ks) {
        half8 bf[8];
#pragma unroll
        for (int nt = 0; nt < 8; ++nt)
            bf[nt] = *(const half8*)(sW + (ks * 8 + nt) * 512 + lane * 8);
#pragma unroll
        for (int nt = 0; nt < 8; ++nt)
            acc[1][nt] = __builtin_amdgcn_mfma_f32_16x16x32_f16(af[ks], bf[nt], acc[1][nt], 0, 0, 0);
    }

    // y = xs@Wc + h*D
#pragma unroll
    for (int hf = 0; hf < 2; ++hf)
#pragma unroll
        for (int nt = 0; nt < 8; ++nt) {
            int col = hf * 128 + nt * 16 + lm;
            float dv = Dv[col];
#pragma unroll
            for (int r = 0; r < 4; ++r)
                acc[hf][nt][r] += (float)h[(rowb + quad * 4 + r) * 256 + col] * dv;
        }
    // wave-local LN
    float mu[4], rs[4];
#pragma unroll
    for (int r = 0; r < 4; ++r) {
        float a = 0.f, b = 0.f;
#pragma unroll
        for (int hf = 0; hf < 2; ++hf)
#pragma unroll
            for (int nt = 0; nt < 8; ++nt) {
                float v = acc[hf][nt][r];
                a += v; b += v * v;
            }
#pragma unroll
        for (int off = 1; off < 16; off <<= 1) {
            a += __shfl_xor(a, off, 64);
            b += __shfl_xor(b, off, 64);
        }
        float m = a * (1.f / 256.f);
        float var = b * (1.f / 256.f) - m * m;
        mu[r] = m;
        rs[r] = rsqrtf(fmaxf(var, 0.f) + 1e-6f);
    }
    // gelu -> g written fp16 into xsT (safe: all xsT reads finished pre-bar2)
#pragma unroll
    for (int hf = 0; hf < 2; ++hf)
#pragma unroll
        for (int nt = 0; nt < 8; ++nt) {
            int col = hf * 128 + nt * 16 + lm;
            float ga = gamma[col], be = beta[col];
#pragma unroll
            for (int r = 0; r < 4; ++r) {
                float hn = (acc[hf][nt][r] - mu[r]) * rs[r] * ga + be;
                int rg = wid * 16 + quad * 4 + r;
                int byte = (2 * col) ^ ((rg & 7) << 4);
                *((_Float16*)((char*)xsT + rg * 512 + byte)) = (_Float16)gelu_(hn);
            }
        }
    __syncthreads();                  // bar4: g visible; all sW(Wc) reads done
    stageWg(0);
    // g A-fragments (xsT, swizzled) -- overlaps the Wglu staging latency
    half8 ag[8];
#pragma unroll
    for (int ks = 0; ks < 8; ++ks) {
        int b = ks * 64 + quad * 16;
        ag[ks] = *(const half8*)((const char*)xsT + rl * 512 + (b ^ ((rl & 7) << 4)));
    }
    asm volatile("s_waitcnt vmcnt(0)" ::: "memory");
    __syncthreads();                  // bar5: sW(Wglu,0) ready

#pragma unroll
    for (int cy = 0; cy < 4; ++cy) {
        f32x4 accg[8];
#pragma unroll
        for (int nt = 0; nt < 8; ++nt) accg[nt] = zero;
#pragma unroll
        for (int ks = 0; ks < 8; ++ks) {
            half8 bf[8];
#pragma unroll
            for (int nt = 0; nt < 8; ++nt)
                bf[nt] = *(const half8*)(sW + (ks * 8 + nt) * 512 + lane * 8);
#pragma unroll
            for (int nt = 0; nt < 8; ++nt)
                accg[nt] = __builtin_amdgcn_mfma_f32_16x16x32_f16(ag[ks], bf[nt], accg[nt], 0, 0, 0);
        }
        // GLU epilogue for n0 = cy*128 (pairs in-thread via Wglu permutation)
        int n0 = cy * 128;
        int jbase = (n0 >> 1) + lm;
        _Float16 xold[4][4];
#pragma unroll
        for (int q = 0; q < 4; ++q)
#pragma unroll
            for (int r = 0; r < 4; ++r)
                xold[q][r] = x[(rowb + quad * 4 + r) * 256 + jbase + q * 16];
#pragma unroll
        for (int q = 0; q < 4; ++q) {
            float b1v = bias[n0 + (2 * q) * 16 + lm];
            float b2v = bias[n0 + (2 * q + 1) * 16 + lm];
            int jcol = jbase + q * 16;
#pragma unroll
            for (int r = 0; r < 4; ++r) {
                float u1 = accg[2 * q][r] + b1v;
                float u2 = accg[2 * q + 1][r] + b2v;
                float gl = u1 * sigmoidf_(u2);
                int idx = (rowb + quad * 4 + r) * 256 + jcol;
                x[idx] = (_Float16)((float)xold[q][r] + gl);   // fp16 residual
            }
        }
        if (cy < 3) {
            __syncthreads();          // all waves done reading sW(Wglu,cy)
            stageWg((cy + 1) * 128);
            asm volatile("s_waitcnt vmcnt(0)" ::: "memory");
            __syncthreads();
        }
    }
}

// k9 v2: deep-MLP streaming GEMM for the output projection.
__global__ __launch_bounds__(256, 2) void s5_k9_gemm_out(const _Float16* __restrict__ A,
                                                         const _Float16* __restrict__ Wt,
                                                         const float* __restrict__ bout,
                                                         float* __restrict__ out) {
    __shared__ _Float16 sW[32 * 512];        // chunk c = ks*4 + n16
    int tid = threadIdx.x, wid = tid >> 6, lane = tid & 63;
    int lm = lane & 15, quad = lane >> 4;
    int m0 = blockIdx.x * 128;
#pragma unroll
    for (int i = 0; i < 8; ++i) {
        int c = i * 4 + wid;
        int ks = c >> 2, n16 = c & 3;
        gll16(Wt + (n16 * 16 + lm) * 256 + ks * 32 + quad * 8, sW + c * 512);
    }
    int rowb = m0 + wid * 32;
    half8 af[2][8];
#pragma unroll
    for (int mt = 0; mt < 2; ++mt)
#pragma unroll
        for (int ks = 0; ks < 8; ++ks)
            af[mt][ks] = *(const half8*)(A + (rowb + mt * 16 + lm) * 256 + ks * 32 + quad * 8);
    asm volatile("s_waitcnt vmcnt(0)" ::: "memory");
    __syncthreads();

    f32x4 zero = {0.f, 0.f, 0.f, 0.f};
    f32x4 acc[2][4];
#pragma unroll
    for (int mt = 0; mt < 2; ++mt)
#pragma unroll
        for (int nt = 0; nt < 4; ++nt) acc[mt][nt] = zero;
#pragma unroll
    for (int ks = 0; ks < 8; ++ks) {
        half8 bf[4];
#pragma unroll
        for (int nt = 0; nt < 4; ++nt)
            bf[nt] = *(const half8*)(sW + (ks * 4 + nt) * 512 + lane * 8);
#pragma unroll
        for (int mt = 0; mt < 2; ++mt)
#pragma unroll
            for (int nt = 0; nt < 4; ++nt)
                acc[mt][nt] = __builtin_amdgcn_mfma_f32_16x16x32_f16(af[mt][ks], bf[nt], acc[mt][nt], 0, 0, 0);
    }
#pragma unroll
    for (int mt = 0; mt < 2; ++mt)
#pragma unroll
        for (int nt = 0; nt < 4; ++nt) {
            int col = nt * 16 + lm;
            float bv = bout[col];
#pragma unroll
            for (int r = 0; r < 4; ++r) {
                int row = rowb + mt * 16 + quad * 4 + r;
                out[row * 64 + col] = acc[mt][nt][r] + bv;
            }
        }
}

// --------------------------- workspace layout ------------------------------
constexpr size_t OFF_X    = 0;                         // half L*256 residual x  16.8MB
constexpr size_t OFF_BU   = 33554432;                  // half L*256 Bu
constexpr size_t OFF_H    = 67108864;                  // half L*256 (h)
constexpr size_t OFF_WBU  = 100663296;                 // half 4*256*256
constexpr size_t OFF_WC   = OFF_WBU + 524288;
constexpr size_t OFF_WGLU = OFF_WC + 524288;           // half 4*512*256
constexpr size_t OFF_WOUT = OFF_WGLU + 1048576;        // half 64*256
constexpr size_t OFF_BGLU = OFF_WOUT + 32768;          // f32 4*512
constexpr size_t OFF_AR   = OFF_BGLU + 8192;
constexpr size_t OFF_AI   = OFF_AR + 2048;
constexpr size_t OFF_CBR  = OFF_AI + 2048;
constexpr size_t OFF_CBI  = OFF_CBR + 2048;
constexpr size_t OFF_ATR  = OFF_CBI + 2048;
constexpr size_t OFF_ATI  = OFF_ATR + 2048;
constexpr size_t OFF_ALP  = OFF_ATI + 2048;
constexpr size_t OFF_RALP = OFF_ALP + 2048;
constexpr size_t OFF_X0H  = OFF_RALP + 2048;           // half 256
constexpr size_t OFF_CARRI= OFF_X0H + 1024;            // f32x2 NCH*128 (512KB)

extern "C" void kernel_launch(void* const* d_in, const int* in_sizes, int n_in,
                              void* d_out, int out_size, void* d_ws, size_t ws_size,
                              hipStream_t stream) {
    (void)in_sizes; (void)n_in; (void)out_size; (void)ws_size;
    const float* latent    = (const float*)d_in[0];
    const float* W_expand  = (const float*)d_in[1];
    const float* b_expand  = (const float*)d_in[2];
    const float* norm_s    = (const float*)d_in[3];
    const float* norm_b    = (const float*)d_in[4];
    const float* Lre       = (const float*)d_in[5];
    const float* Lim       = (const float*)d_in[6];
    const float* Bre       = (const float*)d_in[7];
    const float* Bim       = (const float*)d_in[8];
    const float* Cre       = (const float*)d_in[9];
    const float* Cim       = (const float*)d_in[10];
    const float* Dv        = (const float*)d_in[11];
    const float* lstep     = (const float*)d_in[12];
    const float* W1        = (const float*)d_in[13];
    const float* b1        = (const float*)d_in[14];
    const float* W2        = (const float*)d_in[15];
    const float* b2        = (const float*)d_in[16];
    const float* Wout      = (const float*)d_in[17];
    const float* bout      = (const float*)d_in[18];

    char* ws = (char*)d_ws;
    _Float16* x    = (_Float16*)(ws + OFF_X);
    _Float16* Buh  = (_Float16*)(ws + OFF_BU);                 // fp16 Bu (16.8MB)
    _Float16* hbuf = (_Float16*)(ws + OFF_H);
    _Float16* Wbu  = (_Float16*)(ws + OFF_WBU);
    _Float16* Wc   = (_Float16*)(ws + OFF_WC);
    _Float16* Wglu = (_Float16*)(ws + OFF_WGLU);
    _Float16* WoutT= (_Float16*)(ws + OFF_WOUT);
    float* bglu = (float*)(ws + OFF_BGLU);
    float* aR  = (float*)(ws + OFF_AR);
    float* aI  = (float*)(ws + OFF_AI);
    float* cbR = (float*)(ws + OFF_CBR);
    float* cbI = (float*)(ws + OFF_CBI);
    float* aTR = (float*)(ws + OFF_ATR);
    float* aTI = (float*)(ws + OFF_ATI);
    float* alp = (float*)(ws + OFF_ALP);
    float* ralp= (float*)(ws + OFF_RALP);
    _Float16* x0h = (_Float16*)(ws + OFF_X0H);
    float* carRI=(float*)(ws + OFF_CARRI);

    s5_k0a<<<1, 512, 0, stream>>>(Lre, Lim, lstep, aR, aI, cbR, cbI, aTR, aTI, alp, ralp);
    s5_k0b<<<256, 256, 0, stream>>>(Bre, Bim, Cre, Cim, W1, W2, b1, b2, Wout,
                                    cbR, cbI, alp, ralp, Wbu, Wc, Wglu, WoutT, bglu);
    s5_k0c<<<1, 256, 0, stream>>>(latent, W_expand, b_expand, x0h);
    s5_k1_fill<<<4096, 256, 0, stream>>>(x0h, x);

    for (int l = 0; l < 4; ++l) {
        s5_k3_lngemm<<<256, 512, 0, stream>>>(x, Wbu + l * 65536,
                                              norm_s + l * 256, norm_b + l * 256,
                                              aR + l * 128, aI + l * 128,
                                              hbuf, Buh, carRI);
        s5_k7_mega<<<256, 512, 0, stream>>>(Buh, carRI, Wc + l * 65536, Wglu + l * 131072,
                                            hbuf,
                                            aR + l * 128, aI + l * 128,
                                            aTR + l * 128, aTI + l * 128,
                                            Dv + l * 256,
                                            norm_s + l * 256, norm_b + l * 256,
                                            bglu + l * 512, x);
    }
    s5_k9_gemm_out<<<256, 256, 0, stream>>>(x, WoutT, bout, (float*)d_out);
}